// Round 7
// baseline (567.532 us; speedup 1.0000x reference)
//
#include <hip/hip_runtime.h>

// y[n] = beta0 + sum_c X[n,c]*(beta[c] + Z[n,c]),  Z = X @ triu(Theta,1)
// R7: X-panel-resident GEMM. conv passes write PRE-SWIZZLED bf16 Xb and
// triu^T Tt into d_ws. Each block owns 128 rows: X k-half panel (128 KB)
// resident in LDS, K-loop streams ONLY B-tiles (16 KB, L2-hot Theta) with
// reg-staged prefetch. c-tiles 0,1 contract in phase 0; c-tiles 2,3 hold
// persistent accumulators across the panel swap and contract in phase 1 —
// all contractions read X from LDS. Diagonal ni-skip. Direct y write
// (shfl + LDS reduce), no atomics. 512 identical blocks, 8 waves.

typedef __bf16 bf16_t;
typedef bf16_t bf16x8 __attribute__((ext_vector_type(8)));
typedef float f32x4 __attribute__((ext_vector_type(4)));
typedef unsigned short u16;
typedef u16 u16x4 __attribute__((ext_vector_type(4)));
typedef u16 u16x8 __attribute__((ext_vector_type(8)));

#define N_ROWS 65536
#define P_DIM  1024

static __device__ __forceinline__ u16 f2bf(float f) {
  unsigned u = __builtin_bit_cast(unsigned, f);
  u += 0x7FFFu + ((u >> 16) & 1u);   // round-to-nearest-even
  return (u16)(u >> 16);
}
static __device__ __forceinline__ float bf2f(u16 v) {
  return __builtin_bit_cast(float, ((unsigned)v) << 16);
}

// global(16B/lane, per-lane src) -> LDS direct (wave-uniform dest + lane*16).
static __device__ __forceinline__ void gload16(const void* g, void* lds_base) {
  __builtin_amdgcn_global_load_lds(
      (const __attribute__((address_space(1))) unsigned char*)g,
      (__attribute__((address_space(3))) unsigned char*)lds_base, 16, 0, 0);
}

__global__ void __launch_bounds__(256)
init_y(float* __restrict__ y, const float* __restrict__ beta0) {
  int i = blockIdx.x * blockDim.x + threadIdx.x;
  if (i < N_ROWS) y[i] = beta0[0];
}

// ---- conv 1: X f32 -> bf16, row-quad-XOR swizzled within each 64-quad half.
// Stored quad position p = q ^ (row&7)  (within each half) -> linear
// global_load_lds of a row-half lands so LDS pos p holds original quad
// p^(row&7); readers apply the same XOR. Involution both sides (rule 21).
__global__ void __launch_bounds__(256)
conv_x(const float* __restrict__ X, u16* __restrict__ Xb) {
  const size_t nq = (size_t)N_ROWS * P_DIM / 8;   // quads
  const size_t stride = (size_t)gridDim.x * 256;
  for (size_t i = (size_t)blockIdx.x * 256 + threadIdx.x; i < nq; i += stride) {
    const int row  = (int)(i >> 7);
    const int q128 = (int)(i & 127);
    const int half = q128 >> 6;
    const int q64  = q128 & 63;
    f32x4 a = *(const f32x4*)(X + i * 8);
    f32x4 b = *(const f32x4*)(X + i * 8 + 4);
    u16x8 w;
    #pragma unroll
    for (int j = 0; j < 4; ++j) { w[j] = f2bf(a[j]); w[j + 4] = f2bf(b[j]); }
    *(u16x8*)(Xb + (size_t)row * 1024 + half * 512 + (size_t)((q64 ^ (row & 7)) * 8)) = w;
  }
}

// ---- conv 2: Tt[c][k] = (k<c) ? bf16(Theta[k][c]) : 0, with per-32k-group
// quad swizzle: within group, stored quad = q ^ ((c>>1)&3).
__global__ void __launch_bounds__(128)
conv_theta(const float* __restrict__ Theta, u16* __restrict__ Tt) {
  __shared__ float tile[32][33];
  const int tid = threadIdx.x;         // 0..127
  const int k0  = blockIdx.x * 32;
  const int c0  = blockIdx.y * 32;
  {
    const int tx = tid & 31;           // c within tile
    const int rb = tid >> 5;           // 0..3
    #pragma unroll
    for (int i = 0; i < 8; ++i) {
      int kl = rb * 8 + i;
      tile[kl][tx] = Theta[(size_t)(k0 + kl) * P_DIM + c0 + tx];
    }
  }
  __syncthreads();
  {
    const int cl = tid >> 2;           // 0..31
    const int qt = tid & 3;            // quad within the 32-k tile
    const int cg = c0 + cl;
    u16x8 w;
    #pragma unroll
    for (int e = 0; e < 8; ++e) {
      int kg = k0 + qt * 8 + e;
      float v = tile[qt * 8 + e][cl];
      w[e] = (kg < cg) ? f2bf(v) : (u16)0;
    }
    *(u16x8*)(Tt + (size_t)cg * 1024 + blockIdx.x * 32 + (size_t)((qt ^ ((cg >> 1) & 3)) * 8)) = w;
  }
}

// ---- main kernel: 512 blocks x 512 threads (8 waves, grid 2x4, wave 64x64) ----
__global__ void __launch_bounds__(512, 2)
gemm_panel(const u16* __restrict__ Xb, const u16* __restrict__ Tt,
           const float* __restrict__ beta, const float* __restrict__ beta0,
           float* __restrict__ y)
{
  __shared__ __align__(16) u16 P[128 * 512];    // 128 KB X panel (k-half)
  __shared__ __align__(16) u16 Bt[256 * 32];    // 16 KB B-tile
  __shared__ float Red[4 * 128];                // 2 KB cross-wave reduce

  const int m0 = blockIdx.x * 128;

  const int tid  = threadIdx.x;
  const int lane = tid & 63;
  const int wid  = tid >> 6;           // 0..7
  const int wm   = wid >> 2;           // 0..1  (64-row half)
  const int wn   = wid & 3;            // 0..3  (64-col quarter of the 256 c-tile)
  const int l15  = lane & 15;
  const int lg   = lane >> 4;

  // B staging geometry: thread -> (c row, 32B half of its 64B k-slice)
  const int bc   = tid >> 1;           // 0..255
  const int boff = (tid & 1) * 16;     // u16 offset 0 or 16

  float ysum[4][4];
  #pragma unroll
  for (int mi = 0; mi < 4; ++mi)
    #pragma unroll
    for (int r = 0; r < 4; ++r)
      ysum[mi][r] = 0.0f;

  #define ZERO_ACC(A)                                                          \
    _Pragma("unroll")                                                          \
    for (int mi = 0; mi < 4; ++mi)                                             \
      _Pragma("unroll")                                                        \
      for (int ni = 0; ni < 4; ++ni)                                           \
        A[mi][ni] = (f32x4)0.0f;

  #define LOAD_PANEL(H)                                                        \
    {                                                                          \
      __syncthreads();  /* all prior panel readers done */                     \
      _Pragma("unroll")                                                        \
      for (int i = 0; i < 16; ++i) {                                           \
        const int r_ = wid * 16 + i;                                           \
        gload16(Xb + (size_t)(m0 + r_) * 1024 + (H) * 512 + lane * 8,          \
                &P[r_ * 512]);                                                 \
      }                                                                        \
      asm volatile("s_waitcnt vmcnt(0)" ::: "memory");                         \
      __syncthreads();                                                         \
    }

  // Segment: K-tiles [KLO,KHI) of c-tile CT accumulated into ACC.
  // B(kt+1) prefetched to regs during MFMA of kt; reg->LDS after barrier.
  // GUARD: diagonal band -> wave-uniform ni skip of all-zero B subtiles.
  #define RUN_SEG(ACC, CT, KLO, KHI, GUARD, H)                                 \
    {                                                                          \
      __syncthreads();                                                         \
      {                                                                        \
        const u16* s_ = Tt + (size_t)((CT) * 256 + bc) * 1024 + (KLO) * 32 + boff; \
        u16x8 t0_ = *(const u16x8*)(s_);                                       \
        u16x8 t1_ = *(const u16x8*)(s_ + 8);                                   \
        *(u16x8*)&Bt[bc * 32 + boff]     = t0_;                                \
        *(u16x8*)&Bt[bc * 32 + boff + 8] = t1_;                                \
      }                                                                        \
      __syncthreads();                                                         \
      for (int kt = (KLO); kt < (KHI); ++kt) {                                 \
        u16x8 nb0, nb1;                                                        \
        const bool pre_ = (kt + 1 < (KHI));                                    \
        if (pre_) {                                                            \
          const u16* s_ = Tt + (size_t)((CT) * 256 + bc) * 1024 + (kt + 1) * 32 + boff; \
          nb0 = *(const u16x8*)(s_);                                           \
          nb1 = *(const u16x8*)(s_ + 8);                                       \
        }                                                                      \
        const int ktl_ = kt - (H) * 16;                                        \
        bf16x8 af[4], bfr[4];                                                  \
        _Pragma("unroll")                                                      \
        for (int mi = 0; mi < 4; ++mi) {                                       \
          const int rw_ = wm * 64 + mi * 16 + l15;                             \
          u16x8 v_ = *(const u16x8*)&P[rw_ * 512 + ((ktl_ * 4 + lg) ^ (rw_ & 7)) * 8]; \
          af[mi] = __builtin_bit_cast(bf16x8, v_);                             \
        }                                                                      \
        _Pragma("unroll")                                                      \
        for (int ni = 0; ni < 4; ++ni) {                                       \
          const int cl_ = wn * 64 + ni * 16 + l15;                             \
          u16x8 v_ = *(const u16x8*)&Bt[cl_ * 32 + (lg ^ ((cl_ >> 1) & 3)) * 8]; \
          bfr[ni] = __builtin_bit_cast(bf16x8, v_);                            \
        }                                                                      \
        int nlo_ = 0;                                                          \
        if (GUARD) { nlo_ = 2 * kt - 16 * (CT) - 4 * wn; nlo_ = nlo_ < 0 ? 0 : nlo_; } \
        _Pragma("unroll")                                                      \
        for (int mi = 0; mi < 4; ++mi)                                         \
          _Pragma("unroll")                                                    \
          for (int ni = 0; ni < 4; ++ni)                                       \
            if (!(GUARD) || ni >= nlo_)                                        \
              ACC[mi][ni] = __builtin_amdgcn_mfma_f32_16x16x32_bf16(af[mi], bfr[ni], ACC[mi][ni], 0, 0, 0); \
        if (pre_) {                                                            \
          __syncthreads();                                                     \
          *(u16x8*)&Bt[bc * 32 + boff]     = nb0;                              \
          *(u16x8*)&Bt[bc * 32 + boff + 8] = nb1;                              \
          __syncthreads();                                                     \
        }                                                                      \
      }                                                                        \
    }

  // Contraction: ysum += (ACC + beta) * X, X read from the resident panel.
  #define CONTRACT(ACC, CT, H)                                                 \
    {                                                                          \
      _Pragma("unroll")                                                        \
      for (int ni = 0; ni < 4; ++ni) {                                         \
        const int cg_ = (CT) * 256 + wn * 64 + ni * 16 + l15;                  \
        const float bv_ = beta[cg_];                                           \
        const int ch_ = cg_ - (H) * 512;                                       \
        _Pragma("unroll")                                                      \
        for (int mi = 0; mi < 4; ++mi) {                                       \
          _Pragma("unroll")                                                    \
          for (int r = 0; r < 4; ++r) {                                        \
            const int rw_ = wm * 64 + mi * 16 + lg * 4 + r;                    \
            float xv_ = bf2f(P[rw_ * 512 + ((ch_ >> 3) ^ (rw_ & 7)) * 8 + (ch_ & 7)]); \
            ysum[mi][r] += (ACC[mi][ni][r] + bv_) * xv_;                       \
          }                                                                    \
        }                                                                      \
      }                                                                        \
    }

  f32x4 accA[4][4], acc2[4][4], acc3[4][4];

  // ================= phase 0: panel = k in [0,512) =================
  LOAD_PANEL(0)

  ZERO_ACC(accA)
  RUN_SEG(accA, 0, 0, 8, true, 0)       // ct0: k<256, all diagonal band
  CONTRACT(accA, 0, 0)

  ZERO_ACC(accA)
  RUN_SEG(accA, 1, 0, 8, false, 0)      // ct1: below-diag part
  RUN_SEG(accA, 1, 8, 16, true, 0)      // ct1: diagonal band
  CONTRACT(accA, 1, 0)

  ZERO_ACC(acc2)
  RUN_SEG(acc2, 2, 0, 16, false, 0)     // ct2: k<512 (dense), acc persists

  ZERO_ACC(acc3)
  RUN_SEG(acc3, 3, 0, 16, false, 0)     // ct3: k<512 (dense), acc persists

  // ================= phase 1: panel = k in [512,1024) =================
  LOAD_PANEL(1)

  RUN_SEG(acc2, 2, 16, 24, true, 1)     // ct2: diagonal band
  CONTRACT(acc2, 2, 1)

  RUN_SEG(acc3, 3, 16, 24, false, 1)    // ct3: below-diag
  RUN_SEG(acc3, 3, 24, 32, true, 1)     // ct3: diagonal band
  CONTRACT(acc3, 3, 1)

  #undef ZERO_ACC
  #undef LOAD_PANEL
  #undef RUN_SEG
  #undef CONTRACT

  // ---- reduce: 16-lane shfl (c-direction), then cross-wn via LDS ----
  #pragma unroll
  for (int m = 1; m < 16; m <<= 1)
    #pragma unroll
    for (int mi = 0; mi < 4; ++mi)
      #pragma unroll
      for (int r = 0; r < 4; ++r)
        ysum[mi][r] += __shfl_xor(ysum[mi][r], m);

  __syncthreads();   // Red aliases nothing, but order vs last contraction reads
  if (l15 == 0) {
    #pragma unroll
    for (int mi = 0; mi < 4; ++mi)
      #pragma unroll
      for (int r = 0; r < 4; ++r)
        Red[wn * 128 + wm * 64 + mi * 16 + lg * 4 + r] = ysum[mi][r];
  }
  __syncthreads();
  if (tid < 128) {
    float s = beta0[0] + Red[tid] + Red[128 + tid] + Red[256 + tid] + Red[384 + tid];
    y[m0 + tid] = s;
  }
}

// ================= fallback (R1 kernel, 128x128) if ws too small =================
#define LDT 40
__global__ void __launch_bounds__(256)
fused_quad_fallback(const float* __restrict__ X, const float* __restrict__ beta,
                    const float* __restrict__ Theta, float* __restrict__ y)
{
  __shared__ __align__(16) u16 Alds[128 * LDT];
  __shared__ __align__(16) u16 Blds[128 * LDT];

  const int bid = blockIdx.x;
  const int bn  = bid & 7;
  const int bm  = bid >> 3;
  const int c0  = bn * 128;
  const int m0  = bm * 128;
  const int nkt = (bn + 1) * 4;

  const int tid  = threadIdx.x;
  const int lane = tid & 63;
  const int wid  = tid >> 6;
  const int wm   = wid >> 1;
  const int wn   = wid & 1;
  const int l15  = lane & 15;
  const int lg   = lane >> 4;

  f32x4 acc[4][4];
  #pragma unroll
  for (int i = 0; i < 4; ++i)
    #pragma unroll
    for (int j = 0; j < 4; ++j)
      acc[i][j] = (f32x4)0.0f;

  const int arow  = tid >> 1;
  const int ahalf = (tid & 1) * 16;
  const int kb4 = (tid >> 5) * 4;
  const int cb4 = (tid & 31) * 4;

  for (int kt = 0; kt < nkt; ++kt) {
    const int k0 = kt * 32;
    __syncthreads();
    {
      const f32x4* p = (const f32x4*)(X + (size_t)(m0 + arow) * P_DIM + k0 + ahalf);
      f32x4 v0 = p[0], v1 = p[1], v2 = p[2], v3 = p[3];
      u16x8 w0, w1;
      #pragma unroll
      for (int i = 0; i < 4; ++i) {
        w0[i] = f2bf(v0[i]); w0[i + 4] = f2bf(v1[i]);
        w1[i] = f2bf(v2[i]); w1[i + 4] = f2bf(v3[i]);
      }
      *(u16x8*)&Alds[arow * LDT + ahalf]     = w0;
      *(u16x8*)&Alds[arow * LDT + ahalf + 8] = w1;
    }
    {
      float e[4][4];
      #pragma unroll
      for (int i = 0; i < 4; ++i) {
        f32x4 r = *(const f32x4*)(Theta + (size_t)(k0 + kb4 + i) * P_DIM + c0 + cb4);
        #pragma unroll
        for (int j = 0; j < 4; ++j)
          e[i][j] = ((k0 + kb4 + i) < (c0 + cb4 + j)) ? r[j] : 0.0f;
      }
      #pragma unroll
      for (int j = 0; j < 4; ++j) {
        u16x4 wv;
        #pragma unroll
        for (int i = 0; i < 4; ++i) wv[i] = f2bf(e[i][j]);
        *(u16x4*)&Blds[(cb4 + j) * LDT + kb4] = wv;
      }
    }
    __syncthreads();

    bf16x8 af[4], bfr[4];
    #pragma unroll
    for (int mi = 0; mi < 4; ++mi) {
      u16x8 t = *(const u16x8*)&Alds[(wm * 64 + mi * 16 + l15) * LDT + lg * 8];
      af[mi] = __builtin_bit_cast(bf16x8, t);
    }
    #pragma unroll
    for (int ni = 0; ni < 4; ++ni) {
      u16x8 t = *(const u16x8*)&Blds[(wn * 64 + ni * 16 + l15) * LDT + lg * 8];
      bfr[ni] = __builtin_bit_cast(bf16x8, t);
    }
    #pragma unroll
    for (int mi = 0; mi < 4; ++mi)
      #pragma unroll
      for (int ni = 0; ni < 4; ++ni)
        acc[mi][ni] = __builtin_amdgcn_mfma_f32_16x16x32_bf16(af[mi], bfr[ni], acc[mi][ni], 0, 0, 0);
  }

  float ysum[4][4];
  #pragma unroll
  for (int mi = 0; mi < 4; ++mi)
    #pragma unroll
    for (int r = 0; r < 4; ++r)
      ysum[mi][r] = 0.0f;

  #pragma unroll
  for (int ni = 0; ni < 4; ++ni) {
    const int col = c0 + wn * 64 + ni * 16 + l15;
    const float bta = beta[col];
    #pragma unroll
    for (int mi = 0; mi < 4; ++mi) {
      const int rowb = m0 + wm * 64 + mi * 16 + lg * 4;
      #pragma unroll
      for (int r = 0; r < 4; ++r) {
        float xv = X[(size_t)(rowb + r) * P_DIM + col];
        ysum[mi][r] += (acc[mi][ni][r] + bta) * xv;
      }
    }
  }

  #pragma unroll
  for (int m = 1; m < 16; m <<= 1)
    #pragma unroll
    for (int mi = 0; mi < 4; ++mi)
      #pragma unroll
      for (int r = 0; r < 4; ++r)
        ysum[mi][r] += __shfl_xor(ysum[mi][r], m);

  if (l15 == 0) {
    #pragma unroll
    for (int mi = 0; mi < 4; ++mi)
      #pragma unroll
      for (int r = 0; r < 4; ++r)
        atomicAdd(&y[m0 + wm * 64 + mi * 16 + lg * 4 + r], ysum[mi][r]);
  }
}

extern "C" void kernel_launch(void* const* d_in, const int* in_sizes, int n_in,
                              void* d_out, int out_size, void* d_ws, size_t ws_size,
                              hipStream_t stream) {
  const float* X     = (const float*)d_in[0];
  const float* beta0 = (const float*)d_in[1];
  const float* beta  = (const float*)d_in[2];
  const float* Theta = (const float*)d_in[3];
  float* y = (float*)d_out;

  const size_t need = (size_t)N_ROWS * P_DIM * 2 + (size_t)P_DIM * P_DIM * 2;
  if (ws_size >= need) {
    u16* Xb = (u16*)d_ws;
    u16* Tt = Xb + (size_t)N_ROWS * P_DIM;
    conv_x<<<2048, 256, 0, stream>>>(X, Xb);
    conv_theta<<<dim3(32, 32), 128, 0, stream>>>(Theta, Tt);
    gemm_panel<<<N_ROWS / 128, 512, 0, stream>>>(Xb, Tt, beta, beta0, y);
  } else {
    init_y<<<N_ROWS / 256, 256, 0, stream>>>(y, beta0);
    fused_quad_fallback<<<(N_ROWS / 128) * (P_DIM / 128), 256, 0, stream>>>(X, beta, Theta, y);
  }
}

// Round 9
// 247.626 us; speedup vs baseline: 2.2919x; 2.2919x over previous
//
#include <hip/hip_runtime.h>

// y[n] = beta0 + sum_c X[n,c]*(beta[c] + Z[n,c]),  Z = X @ triu(Theta,1)
// R9 = R8 + fix: B-panel staging now reads Tt at (c0 + local_c) (R8 read
// panel-local columns for every cc, corrupting 19/20 panels).
// Design: B-stationary, M-streamed. conv passes: Xb = linear bf16 X; Tt =
// triu^T bf16 Theta, quad-XOR pre-swizzled (Tt[c][Q'] holds quad Q'^(c&7)).
// Each block owns one (cc 128-col, kc 256-k) panel + 256 rows: B panel (64KB)
// staged to LDS once (single barrier), then a barrier-free M-stream: per
// 32-row strip-pair, unrolled kk-loop of {2 A-loads, 8 ds_read_b128, 16 MFMA}.
// Transposed MFMA (D[c,n], lane=n) makes the fused contraction read X
// row-contiguously. Partial y summed bilinearly via atomicAdd (beta folded
// into kc==0 panels, beta0 into panel (0,0)). 5120 blocks, 2 resident/CU.

typedef __bf16 bf16_t;
typedef bf16_t bf16x8 __attribute__((ext_vector_type(8)));
typedef float f32x4 __attribute__((ext_vector_type(4)));
typedef unsigned short u16;
typedef u16 u16x4 __attribute__((ext_vector_type(4)));
typedef u16 u16x8 __attribute__((ext_vector_type(8)));

#define N_ROWS 65536
#define P_DIM  1024
#define ROWS_PER_BLK 256
#define NPANEL 20

static __device__ __forceinline__ u16 f2bf(float f) {
  unsigned u = __builtin_bit_cast(unsigned, f);
  u += 0x7FFFu + ((u >> 16) & 1u);   // round-to-nearest-even
  return (u16)(u >> 16);
}
static __device__ __forceinline__ float bf2f(u16 v) {
  return __builtin_bit_cast(float, ((unsigned)v) << 16);
}

// global(16B/lane, per-lane src) -> LDS direct (wave-uniform dest + lane*16).
static __device__ __forceinline__ void gload16(const void* g, void* lds_base) {
  __builtin_amdgcn_global_load_lds(
      (const __attribute__((address_space(1))) unsigned char*)g,
      (__attribute__((address_space(3))) unsigned char*)lds_base, 16, 0, 0);
}

__global__ void __launch_bounds__(256)
zero_y(float* __restrict__ y) {
  int i = blockIdx.x * blockDim.x + threadIdx.x;
  if (i < N_ROWS) y[i] = 0.0f;
}

__global__ void __launch_bounds__(256)
init_y(float* __restrict__ y, const float* __restrict__ beta0) {
  int i = blockIdx.x * blockDim.x + threadIdx.x;
  if (i < N_ROWS) y[i] = beta0[0];
}

// ---- conv 1: X f32 -> bf16, LINEAR layout ----
__global__ void __launch_bounds__(256)
conv_x(const float* __restrict__ X, u16* __restrict__ Xb) {
  const size_t total8 = (size_t)N_ROWS * P_DIM / 8;
  const size_t stride = (size_t)gridDim.x * 256;
  for (size_t i = (size_t)blockIdx.x * 256 + threadIdx.x; i < total8; i += stride) {
    f32x4 a = *(const f32x4*)(X + i * 8);
    f32x4 b = *(const f32x4*)(X + i * 8 + 4);
    u16x8 w;
    #pragma unroll
    for (int j = 0; j < 4; ++j) { w[j] = f2bf(a[j]); w[j + 4] = f2bf(b[j]); }
    *(u16x8*)(Xb + i * 8) = w;
  }
}

// ---- conv 2: Tt[c][Q'] = quad Q = Q'^(c&7) of column c, triu-masked:
// elems k=8Q..8Q+7, value = (k<c) ? bf16(Theta[k][c]) : 0. Quad-XOR baked in
// so the GEMM stages linearly (gload16) and reads conflict-free (rule 21).
__global__ void __launch_bounds__(128)
conv_theta(const float* __restrict__ Theta, u16* __restrict__ Tt) {
  __shared__ float tile[32][33];
  const int tid = threadIdx.x;         // 0..127
  const int k0  = blockIdx.x * 32;
  const int c0  = blockIdx.y * 32;
  {
    const int tx = tid & 31;           // c within tile
    const int rb = tid >> 5;           // 0..3
    #pragma unroll
    for (int i = 0; i < 8; ++i) {
      int kl = rb * 8 + i;
      tile[kl][tx] = Theta[(size_t)(k0 + kl) * P_DIM + c0 + tx];
    }
  }
  __syncthreads();
  {
    const int cl = tid >> 2;           // 0..31
    const int qt = tid & 3;            // quad within this 32-k tile
    const int c  = c0 + cl;
    const int Q  = blockIdx.x * 4 + qt;  // global quad 0..127
    u16x8 w;
    #pragma unroll
    for (int e = 0; e < 8; ++e) {
      int k = Q * 8 + e;
      float v = tile[qt * 8 + e][cl];
      w[e] = (k < c) ? f2bf(v) : (u16)0;
    }
    *(u16x8*)(Tt + (size_t)c * P_DIM + (size_t)((Q ^ (c & 7)) * 8)) = w;
  }
}

// ---- main kernel: B-stationary panel GEMM + fused contraction ----
__global__ void __launch_bounds__(256, 2)
gemm_bstat(const u16* __restrict__ Xb, const u16* __restrict__ Tt,
           const float* __restrict__ beta, const float* __restrict__ beta0,
           float* __restrict__ y)
{
  __shared__ __align__(16) u16 B[128 * 256];   // 64 KB: [c 128][k 256], rows 512B

  const int bid = blockIdx.x;
  const int pid = bid % NPANEL;
  const int m0  = (bid / NPANEL) * ROWS_PER_BLK;

  // pid -> (cc, kc): kc-chunks per cc = (cc+2)>>1, cum = 1,2,4,6,9,12,16,20
  int cc = 0, base = 0;
  #pragma unroll
  for (int j = 0; j < 8; ++j) {
    int kcj = (j + 2) >> 1;
    if (pid >= base + kcj) { base += kcj; cc = j + 1; }
  }
  const int kc    = pid - base;
  const int kbeg  = kc * 256;
  const int krem  = 128 * (cc + 1) - kbeg;
  const int kkcnt = krem >= 256 ? 8 : 4;       // 8 or 4 (krem is 128 or >=256)
  const int c0    = cc * 128;
  const bool add_beta = (kc == 0);
  const bool add_b0   = (cc == 0 && kc == 0);
  const float b0 = beta0[0];

  const int tid  = threadIdx.x;
  const int lane = tid & 63;
  const int w    = tid >> 6;           // wave 0..3
  const int l15  = lane & 15;
  const int lg   = lane >> 4;

  // ---- stage B panel (once): wave w covers c-pairs [16w, 16w+16) ----
  // Instr i: 1 KB = 2 c-rows; lanes 0..31 -> local c=2pi (512B), 32..63 -> 2pi+1.
  // Source is PRE-SWIZZLED Tt at GLOBAL column c0+c (R8 bug: c0 was missing).
  #pragma unroll
  for (int i = 0; i < 16; ++i) {
    const int pi = w * 16 + i;
    const int c  = 2 * pi + (lane >> 5);
    gload16(Tt + (size_t)(c0 + c) * P_DIM + kbeg + (lane & 31) * 8, &B[pi * 512]);
  }
  asm volatile("s_waitcnt vmcnt(0)" ::: "memory");
  __builtin_amdgcn_sched_barrier(0);
  __builtin_amdgcn_s_barrier();
  __builtin_amdgcn_sched_barrier(0);

  // ---- barrier-free M-stream: wave w owns rows [m0+64w, m0+64w+64) ----
  const int rbase = m0 + w * 64;

  #define KKBODY(KK)                                                            \
    _Pragma("unroll")                                                           \
    for (int kk = 0; kk < (KK); ++kk) {                                         \
      bf16x8 a0, a1, bfr[8];                                                    \
      {                                                                         \
        u16x8 v = *(const u16x8*)(Xb + (size_t)(rowA + l15) * P_DIM + kbeg + kk * 32 + lg * 8); \
        a0 = __builtin_bit_cast(bf16x8, v);                                     \
      }                                                                         \
      {                                                                         \
        u16x8 v = *(const u16x8*)(Xb + (size_t)(rowB + l15) * P_DIM + kbeg + kk * 32 + lg * 8); \
        a1 = __builtin_bit_cast(bf16x8, v);                                     \
      }                                                                         \
      _Pragma("unroll")                                                         \
      for (int ni = 0; ni < 8; ++ni) {                                          \
        const int c_ = ni * 16 + l15;                                           \
        const int qp = (kk * 4 + lg) ^ (c_ & 7);                                \
        u16x8 v = *(const u16x8*)&B[c_ * 256 + qp * 8];                         \
        bfr[ni] = __builtin_bit_cast(bf16x8, v);                                \
      }                                                                         \
      _Pragma("unroll")                                                         \
      for (int ni = 0; ni < 8; ++ni) {                                          \
        acc0[ni] = __builtin_amdgcn_mfma_f32_16x16x32_bf16(bfr[ni], a0, acc0[ni], 0, 0, 0); \
        acc1[ni] = __builtin_amdgcn_mfma_f32_16x16x32_bf16(bfr[ni], a1, acc1[ni], 0, 0, 0); \
      }                                                                         \
    }

  // Contraction: lane holds D[c,n] with n = ROW+l15, c = c0 + ni*16 + lg*4 + r.
  #define CONTRACT(ACC, ROW)                                                    \
    {                                                                           \
      float ys = 0.0f;                                                          \
      _Pragma("unroll")                                                         \
      for (int ni = 0; ni < 8; ++ni) {                                          \
        u16x4 xw = *(const u16x4*)(Xb + (size_t)((ROW) + l15) * P_DIM + c0 + ni * 16 + lg * 4); \
        f32x4 bv = add_beta ? *(const f32x4*)(beta + c0 + ni * 16 + lg * 4) : (f32x4)0.0f; \
        _Pragma("unroll")                                                       \
        for (int r = 0; r < 4; ++r)                                             \
          ys += (ACC[ni][r] + bv[r]) * bf2f(xw[r]);                             \
      }                                                                         \
      ys += __shfl_xor(ys, 16);                                                 \
      ys += __shfl_xor(ys, 32);                                                 \
      if (lane < 16) {                                                          \
        if (add_b0) ys += b0;                                                   \
        atomicAdd(&y[(ROW) + l15], ys);                                        \
      }                                                                         \
    }

  #pragma unroll
  for (int p = 0; p < 2; ++p) {
    const int rowA = rbase + p * 32;
    const int rowB = rowA + 16;
    f32x4 acc0[8], acc1[8];
    #pragma unroll
    for (int ni = 0; ni < 8; ++ni) { acc0[ni] = (f32x4)0.0f; acc1[ni] = (f32x4)0.0f; }

    if (kkcnt == 8) { KKBODY(8) } else { KKBODY(4) }

    CONTRACT(acc0, rowA)
    CONTRACT(acc1, rowB)
  }
  #undef KKBODY
  #undef CONTRACT
}

// ================= fallback (R1 kernel, 128x128) if ws too small =================
#define LDT 40
__global__ void __launch_bounds__(256)
fused_quad_fallback(const float* __restrict__ X, const float* __restrict__ beta,
                    const float* __restrict__ Theta, float* __restrict__ y)
{
  __shared__ __align__(16) u16 Alds[128 * LDT];
  __shared__ __align__(16) u16 Blds[128 * LDT];

  const int bid = blockIdx.x;
  const int bn  = bid & 7;
  const int bm  = bid >> 3;
  const int c0  = bn * 128;
  const int m0  = bm * 128;
  const int nkt = (bn + 1) * 4;

  const int tid  = threadIdx.x;
  const int lane = tid & 63;
  const int wid  = tid >> 6;
  const int wm   = wid >> 1;
  const int wn   = wid & 1;
  const int l15  = lane & 15;
  const int lg   = lane >> 4;

  f32x4 acc[4][4];
  #pragma unroll
  for (int i = 0; i < 4; ++i)
    #pragma unroll
    for (int j = 0; j < 4; ++j)
      acc[i][j] = (f32x4)0.0f;

  const int arow  = tid >> 1;
  const int ahalf = (tid & 1) * 16;
  const int kb4 = (tid >> 5) * 4;
  const int cb4 = (tid & 31) * 4;

  for (int kt = 0; kt < nkt; ++kt) {
    const int k0 = kt * 32;
    __syncthreads();
    {
      const f32x4* p = (const f32x4*)(X + (size_t)(m0 + arow) * P_DIM + k0 + ahalf);
      f32x4 v0 = p[0], v1 = p[1], v2 = p[2], v3 = p[3];
      u16x8 w0, w1;
      #pragma unroll
      for (int i = 0; i < 4; ++i) {
        w0[i] = f2bf(v0[i]); w0[i + 4] = f2bf(v1[i]);
        w1[i] = f2bf(v2[i]); w1[i + 4] = f2bf(v3[i]);
      }
      *(u16x8*)&Alds[arow * LDT + ahalf]     = w0;
      *(u16x8*)&Alds[arow * LDT + ahalf + 8] = w1;
    }
    {
      float e[4][4];
      #pragma unroll
      for (int i = 0; i < 4; ++i) {
        f32x4 r = *(const f32x4*)(Theta + (size_t)(k0 + kb4 + i) * P_DIM + c0 + cb4);
        #pragma unroll
        for (int j = 0; j < 4; ++j)
          e[i][j] = ((k0 + kb4 + i) < (c0 + cb4 + j)) ? r[j] : 0.0f;
      }
      #pragma unroll
      for (int j = 0; j < 4; ++j) {
        u16x4 wv;
        #pragma unroll
        for (int i = 0; i < 4; ++i) wv[i] = f2bf(e[i][j]);
        *(u16x4*)&Blds[(cb4 + j) * LDT + kb4] = wv;
      }
    }
    __syncthreads();

    bf16x8 af[4], bfr[4];
    #pragma unroll
    for (int mi = 0; mi < 4; ++mi) {
      u16x8 t = *(const u16x8*)&Alds[(wm * 64 + mi * 16 + l15) * LDT + lg * 8];
      af[mi] = __builtin_bit_cast(bf16x8, t);
    }
    #pragma unroll
    for (int ni = 0; ni < 4; ++ni) {
      u16x8 t = *(const u16x8*)&Blds[(wn * 64 + ni * 16 + l15) * LDT + lg * 8];
      bfr[ni] = __builtin_bit_cast(bf16x8, t);
    }
    #pragma unroll
    for (int mi = 0; mi < 4; ++mi)
      #pragma unroll
      for (int ni = 0; ni < 4; ++ni)
        acc[mi][ni] = __builtin_amdgcn_mfma_f32_16x16x32_bf16(af[mi], bfr[ni], acc[mi][ni], 0, 0, 0);
  }

  float ysum[4][4];
  #pragma unroll
  for (int mi = 0; mi < 4; ++mi)
    #pragma unroll
    for (int r = 0; r < 4; ++r)
      ysum[mi][r] = 0.0f;

  #pragma unroll
  for (int ni = 0; ni < 4; ++ni) {
    const int col = c0 + wn * 64 + ni * 16 + l15;
    const float bta = beta[col];
    #pragma unroll
    for (int mi = 0; mi < 4; ++mi) {
      const int rowb = m0 + wm * 64 + mi * 16 + lg * 4;
      #pragma unroll
      for (int r = 0; r < 4; ++r) {
        float xv = X[(size_t)(rowb + r) * P_DIM + col];
        ysum[mi][r] += (acc[mi][ni][r] + bta) * xv;
      }
    }
  }

  #pragma unroll
  for (int m = 1; m < 16; m <<= 1)
    #pragma unroll
    for (int mi = 0; mi < 4; ++mi)
      #pragma unroll
      for (int r = 0; r < 4; ++r)
        ysum[mi][r] += __shfl_xor(ysum[mi][r], m);

  if (l15 == 0) {
    #pragma unroll
    for (int mi = 0; mi < 4; ++mi)
      #pragma unroll
      for (int r = 0; r < 4; ++r)
        atomicAdd(&y[m0 + wm * 64 + mi * 16 + lg * 4 + r], ysum[mi][r]);
  }
}

extern "C" void kernel_launch(void* const* d_in, const int* in_sizes, int n_in,
                              void* d_out, int out_size, void* d_ws, size_t ws_size,
                              hipStream_t stream) {
  const float* X     = (const float*)d_in[0];
  const float* beta0 = (const float*)d_in[1];
  const float* beta  = (const float*)d_in[2];
  const float* Theta = (const float*)d_in[3];
  float* y = (float*)d_out;

  const size_t need = (size_t)N_ROWS * P_DIM * 2 + (size_t)P_DIM * P_DIM * 2;
  if (ws_size >= need) {
    u16* Xb = (u16*)d_ws;
    u16* Tt = Xb + (size_t)N_ROWS * P_DIM;
    zero_y<<<N_ROWS / 256, 256, 0, stream>>>(y);
    conv_x<<<2048, 256, 0, stream>>>(X, Xb);
    conv_theta<<<dim3(32, 32), 128, 0, stream>>>(Theta, Tt);
    gemm_bstat<<<(N_ROWS / ROWS_PER_BLK) * NPANEL, 256, 0, stream>>>(Xb, Tt, beta, beta0, y);
  } else {
    init_y<<<N_ROWS / 256, 256, 0, stream>>>(y, beta0);
    fused_quad_fallback<<<(N_ROWS / 128) * (P_DIM / 128), 256, 0, stream>>>(X, beta, Theta, y);
  }
}